// Round 1
// 2133.610 us; speedup vs baseline: 1.0716x; 1.0716x over previous
//
#include <hip/hip_runtime.h>

#define BSZ 8192
#define LH 20
#define NFD 172
#define DD 860        // D = 172*4 + 172
#define DHH 430       // D / 2 heads
#define KP 896        // D padded to mult of 64 (8-phase GEMM uses BK=64; was 864)
#define NQKV 2580     // 3*D
#define LDQ 2816      // 3*D padded to mult of 256 (8-phase tile N=256; was 2688)

typedef float f32x4 __attribute__((ext_vector_type(4)));
typedef __bf16 v8bf16 __attribute__((ext_vector_type(8)));

typedef __attribute__((address_space(3))) void lds_void;
typedef const __attribute__((address_space(1))) void global_void;

static __device__ __forceinline__ unsigned short f2b(float f) {
    union { float f; unsigned u; } U; U.f = f;
    unsigned r = (U.u + 0x7fffu + ((U.u >> 16) & 1u)) >> 16;
    return (unsigned short)r;
}
static __device__ __forceinline__ float b2f(unsigned short x) {
    union { unsigned u; float f; } U; U.u = ((unsigned)x) << 16; return U.f;
}
static __device__ __forceinline__ void async16(const void* g, void* l) {
    __builtin_amdgcn_global_load_lds((global_void*)g, (lds_void*)l, 16, 0, 0);
}

// ---------------------------------------------------------------------------
// Weight convert + zero-pad: src fp32 (N,K) -> dst bf16 (Np,Kp)
// ---------------------------------------------------------------------------
__global__ __launch_bounds__(256) void pad_convert(
    const float* __restrict__ src, unsigned short* __restrict__ dst,
    int N, int K, int Np, int Kp)
{
    int total = Np * Kp;
    for (int i = blockIdx.x * blockDim.x + threadIdx.x; i < total;
         i += gridDim.x * blockDim.x) {
        int n = i / Kp, k = i - (i / Kp) * Kp;
        float v = (n < N && k < K) ? src[(size_t)n * K + k] : 0.f;
        dst[i] = f2b(v);
    }
}

// ---------------------------------------------------------------------------
// Build `full` (chunk rows x KP, bf16), last-event-feat into xbuf cols 172..,
// prev_ts output. One block per (b,j) row.
// ---------------------------------------------------------------------------
__global__ __launch_bounds__(256) void build_kernel(
    const int* __restrict__ nids, const int* __restrict__ hist_nids,
    const int* __restrict__ aids, const int* __restrict__ eids,
    const float* __restrict__ ts, const int* __restrict__ dirs,
    const float* __restrict__ node_emb, const float* __restrict__ edge_emb,
    const float* __restrict__ anony_emb, const float* __restrict__ time_w,
    const float* __restrict__ time_b,
    unsigned short* __restrict__ full, unsigned short* __restrict__ xbuf,
    float* __restrict__ prev_ts, int c0)
{
    int idx = blockIdx.x;
    int b = c0 + idx / LH;
    int j = idx - (idx / LH) * LH;
    int nid = nids[b];
    int hn  = hist_nids[b * LH + j];
    int dir = dirs[b * LH + j];
    int src = dir ? nid : hn;
    int dst = dir ? hn : nid;
    int aid = aids[b * LH + j];
    int eid = eids[b * LH + j];
    float tlast = ts[b * LH + (LH - 1)];
    float dt = tlast - ts[b * LH + j];
    bool last = (j == LH - 1);
    unsigned short* frow = full + (size_t)idx * KP;

    for (int c = threadIdx.x; c < KP; c += blockDim.x) {
        float v;
        if (c < NFD)            v = node_emb[(size_t)src * NFD + c];
        else if (c < 2 * NFD)   v = node_emb[(size_t)dst * NFD + (c - NFD)];
        else if (c < 3 * NFD)   v = anony_emb[(size_t)aid * NFD + (c - 2 * NFD)];
        else if (c < 4 * NFD)   v = edge_emb[(size_t)eid * NFD + (c - 3 * NFD)];
        else if (c < DD) { int tf = c - 4 * NFD; v = cosf(dt * time_w[tf] + time_b[tf]); }
        else                    v = 0.f;
        unsigned short bv = f2b(v);
        if (last) {
            if (c < 4 * NFD) {
                // last_event_feat -> x cols [172, 860); zero the full row entry
                xbuf[(size_t)b * KP + NFD + c] = bv;
                frow[c] = 0;
            } else {
                frow[c] = bv;
                // zero x pad cols [860, KP): c in [688, 688+36)
                if (c < 4 * NFD + 36) xbuf[(size_t)b * KP + NFD + c] = 0;
            }
        } else {
            frow[c] = bv;
        }
    }
    if (last && threadIdx.x == 0) prev_ts[b] = tlast;
}

// ---------------------------------------------------------------------------
// bf16 MFMA GEMM: C[M,N] = A[M,Kp] @ B[N,Kp]^T (+bias, opt relu)
// m97 structure: 128x128 tile, BK=32, 4 waves. Kept for the small epilogue
// GEMMs (E1-E4) where grids are tiny.
// ---------------------------------------------------------------------------
__global__ __launch_bounds__(256) void gemm_bt(
    const unsigned short* __restrict__ A, const unsigned short* __restrict__ B,
    const float* __restrict__ bias, int Kp, int N,
    float* __restrict__ outF, int ldF, int nF,
    unsigned short* __restrict__ outB, int ldB, int nB, int relu)
{
    __shared__ __align__(16) unsigned short As[128 * 32];
    __shared__ __align__(16) unsigned short Bs[128 * 32];
    int tid = threadIdx.x;
    int w = tid >> 6, lane = tid & 63;
    int r = lane & 15, q = lane >> 4;
    int m0 = blockIdx.x * 128;
    int n0 = blockIdx.y * 128;
    int wm = (w >> 1) * 64, wn = (w & 1) * 64;
    f32x4 acc[4][4] = {};
    int ktiles = Kp >> 5;

    for (int kt = 0; kt < ktiles; ++kt) {
        int k0 = kt * 32;
#pragma unroll
        for (int iss = 0; iss < 2; ++iss) {
            int chunk = iss * 256 + w * 64 + lane;       // 0..511
            int mm = chunk >> 2, kc = chunk & 3;
            const unsigned short* ga = A + (size_t)(m0 + mm) * Kp + k0 + kc * 8;
            async16(ga, &As[(size_t)(iss * 256 + w * 64) * 8]);
            const unsigned short* gb = B + (size_t)(n0 + mm) * Kp + k0 + kc * 8;
            async16(gb, &Bs[(size_t)(iss * 256 + w * 64) * 8]);
        }
        __syncthreads();
        v8bf16 af[4], bfr[4];
#pragma unroll
        for (int im = 0; im < 4; ++im)
            af[im] = *(const v8bf16*)&As[(wm + im * 16 + r) * 32 + q * 8];
#pragma unroll
        for (int in = 0; in < 4; ++in)
            bfr[in] = *(const v8bf16*)&Bs[(wn + in * 16 + r) * 32 + q * 8];
#pragma unroll
        for (int im = 0; im < 4; ++im)
#pragma unroll
            for (int in = 0; in < 4; ++in)
                acc[im][in] = __builtin_amdgcn_mfma_f32_16x16x32_bf16(
                    af[im], bfr[in], acc[im][in], 0, 0, 0);
        __syncthreads();
    }

#pragma unroll
    for (int im = 0; im < 4; ++im) {
        int rowb = m0 + wm + im * 16 + q * 4;
#pragma unroll
        for (int in = 0; in < 4; ++in) {
            int col = n0 + wn + in * 16 + r;
            float bv = (col < N) ? bias[col] : 0.f;
#pragma unroll
            for (int reg = 0; reg < 4; ++reg) {
                float v = acc[im][in][reg];
                if (col < N) { v += bv; if (relu) v = fmaxf(v, 0.f); }
                else v = 0.f;
                int rr = rowb + reg;
                if (outF && col < nF) outF[(size_t)rr * ldF + col] = v;
                if (outB && col < nB) outB[(size_t)rr * ldB + col] = f2b(v);
            }
        }
    }
}

// ---------------------------------------------------------------------------
// 256x256 / BK=64 / 8-wave / 8-phase counted-vmcnt GEMM (T2+T3+T4+T5).
// C[M,N] = A[M,Kp] @ B[N,Kp]^T + bias -> bf16 out. Kp % 128 == 0,
// M % 256 == 0, grid.y*256 rows of B must be allocated (zero-padded).
//
// LDS: lds[buf2][op A/B][half][128x64 bf16] = 128 KiB, 1 block/CU.
// Swizzle: byte ^= ((byte>>9)&1)<<5 applied as pre-swizzled GLOBAL source
// (global_load_lds dest must be linear; rule #21) + swizzled ds_read.
// Waits: vmcnt(4) at phases 4 & 8 only (2 half-tiles always in flight);
// vmcnt(0) only in the last iteration's phase 4. sched_barrier(0) after
// each vmcnt pins ds_reads below the wait.
// ---------------------------------------------------------------------------
static __device__ __forceinline__ v8bf16 lds_frag256(
    const unsigned short* t /*256x64 tile*/, int row, int colB /*bytes*/)
{
    int o = row * 128 + (colB ^ (((row >> 2) & 1) << 5));
    return *(const v8bf16*)((const char*)t + o);
}

static __device__ __forceinline__ void stage_half(
    const unsigned short* __restrict__ G, int rowBase, int Kp, int kt,
    unsigned short* lh /*&lds[buf][op][half][0]*/, int w, int lane)
{
#pragma unroll
    for (int l = 0; l < 2; ++l) {
        int rowInHalf = l * 64 + w * 8 + (lane >> 3);
        // inverse-swizzled source column (bit5 of byte col XOR'd with dest bit9)
        int colE = (((lane & 7) * 16) ^ ((lane >> 5) << 5)) >> 1;
        const unsigned short* g =
            G + (size_t)(rowBase + rowInHalf) * Kp + kt * 64 + colE;
        async16(g, lh + l * 4096 + w * 512);   // HW adds lane*16 bytes
    }
}

__global__ __launch_bounds__(512, 2) void gemm_bt_8p(
    const unsigned short* __restrict__ A, const unsigned short* __restrict__ B,
    const float* __restrict__ bias, int Kp, int N,
    unsigned short* __restrict__ outB, int ldB)
{
    __shared__ __align__(16) unsigned short lds[2][2][2][128 * 64];
    const int tid = threadIdx.x;
    const int w = tid >> 6, lane = tid & 63;
    const int r = lane & 15, q = lane >> 4;
    const int m0 = blockIdx.x * 256;
    const int n0 = blockIdx.y * 256;
    const int wm = (w >> 2) * 128, wn = (w & 3) * 64;
    const int nt = Kp >> 6;        // K-tiles of 64
    const int niter = nt >> 1;     // 2 K-tiles per iteration

    f32x4 acc[8][4] = {};

    // prologue: stage A0,B0 (8 loads) + B1 (4 loads); wait A0,B0; B1 in flight
    stage_half(A, m0 + 0,   Kp, 0, &lds[0][0][0][0], w, lane);
    stage_half(A, m0 + 128, Kp, 0, &lds[0][0][1][0], w, lane);
    stage_half(B, n0 + 0,   Kp, 0, &lds[0][1][0][0], w, lane);
    stage_half(B, n0 + 128, Kp, 0, &lds[0][1][1][0], w, lane);
    stage_half(B, n0 + 0,   Kp, 1, &lds[1][1][0][0], w, lane);
    stage_half(B, n0 + 128, Kp, 1, &lds[1][1][1][0], w, lane);
    asm volatile("s_waitcnt vmcnt(4)");
    __builtin_amdgcn_sched_barrier(0);
    __builtin_amdgcn_s_barrier();

    for (int i = 0; i < niter; ++i) {
        const int T = 2 * i;
        const bool notLast = (i + 1 < niter);
#pragma unroll
        for (int tt = 0; tt < 2; ++tt) {               // tile T+tt in buf tt
            const unsigned short* At = &lds[tt][0][0][0];
            const unsigned short* Bt = &lds[tt][1][0][0];
            v8bf16 bf[4][2];
#pragma unroll
            for (int mp = 0; mp < 4; ++mp) {           // phase = tt*4 + mp + 1
                if (mp == 0) {
#pragma unroll
                    for (int in = 0; in < 4; ++in)
#pragma unroll
                        for (int kk = 0; kk < 2; ++kk)
                            bf[in][kk] = lds_frag256(Bt, wn + in * 16 + r,
                                                     kk * 64 + q * 16);
                }
                v8bf16 a0[2], a1[2];
#pragma unroll
                for (int kk = 0; kk < 2; ++kk) {
                    a0[kk] = lds_frag256(At, wm + (mp * 2 + 0) * 16 + r,
                                         kk * 64 + q * 16);
                    a1[kk] = lds_frag256(At, wm + (mp * 2 + 1) * 16 + r,
                                         kk * 64 + q * 16);
                }
                // staging schedule (each target region fully consumed >=1
                // barrier before its overwrite is issued):
                if (tt == 0 && mp == 0)
                    stage_half(A, m0 + 0,   Kp, T + 1, &lds[1][0][0][0], w, lane);
                if (tt == 0 && mp == 1) {
                    stage_half(A, m0 + 128, Kp, T + 1, &lds[1][0][1][0], w, lane);
                    if (notLast)
                        stage_half(B, n0 + 0,   Kp, T + 2, &lds[0][1][0][0], w, lane);
                }
                if (tt == 0 && mp == 2 && notLast)
                    stage_half(B, n0 + 128, Kp, T + 2, &lds[0][1][1][0], w, lane);
                if (tt == 1 && mp == 0 && notLast)
                    stage_half(A, m0 + 0,   Kp, T + 2, &lds[0][0][0][0], w, lane);
                if (tt == 1 && mp == 1 && notLast)
                    stage_half(A, m0 + 128, Kp, T + 2, &lds[0][0][1][0], w, lane);
                if (tt == 1 && mp == 2 && notLast)
                    stage_half(B, n0 + 0,   Kp, T + 3, &lds[1][1][0][0], w, lane);
                if (tt == 1 && mp == 3 && notLast)
                    stage_half(B, n0 + 128, Kp, T + 3, &lds[1][1][1][0], w, lane);

                if (mp == 3) {
                    if (notLast) {
                        asm volatile("s_waitcnt vmcnt(4)");   // keep next B in flight
                    } else if (tt == 0) {
                        asm volatile("s_waitcnt vmcnt(0)");   // drain for last tile
                    }
                    __builtin_amdgcn_sched_barrier(0);
                }
                __builtin_amdgcn_s_barrier();
                asm volatile("s_waitcnt lgkmcnt(0)");
                __builtin_amdgcn_sched_barrier(0);
                __builtin_amdgcn_s_setprio(1);
#pragma unroll
                for (int kk = 0; kk < 2; ++kk)
#pragma unroll
                    for (int in = 0; in < 4; ++in) {
                        acc[mp * 2 + 0][in] = __builtin_amdgcn_mfma_f32_16x16x32_bf16(
                            a0[kk], bf[in][kk], acc[mp * 2 + 0][in], 0, 0, 0);
                        acc[mp * 2 + 1][in] = __builtin_amdgcn_mfma_f32_16x16x32_bf16(
                            a1[kk], bf[in][kk], acc[mp * 2 + 1][in], 0, 0, 0);
                    }
                __builtin_amdgcn_s_setprio(0);
                __builtin_amdgcn_s_barrier();
            }
        }
    }

#pragma unroll
    for (int im = 0; im < 8; ++im) {
        int rowb = m0 + wm + im * 16 + q * 4;
#pragma unroll
        for (int in = 0; in < 4; ++in) {
            int col = n0 + wn + in * 16 + r;
            float bv = (col < N) ? bias[col] : 0.f;
#pragma unroll
            for (int reg = 0; reg < 4; ++reg) {
                float v = (col < N) ? acc[im][in][reg] + bv : 0.f;
                outB[(size_t)(rowb + reg) * ldB + col] = f2b(v);
            }
        }
    }
}

// ---------------------------------------------------------------------------
// Attention per b: S=QK^T via MFMA, softmax w/ mask, pbar = mean_i P,
// mean_ctx[d] = sum_j pbar[j] * V[j,d]  (mean over queries folded into pbar).
// ---------------------------------------------------------------------------
static __device__ __forceinline__ v8bf16 load_frag(
    const unsigned short* row, int colbase, int d0)
{
    union { unsigned u[4]; v8bf16 v; unsigned short s[8]; } U;
    if (d0 + 8 <= DHH) {
        const unsigned* p = (const unsigned*)(row + colbase + d0);
        U.u[0] = p[0]; U.u[1] = p[1]; U.u[2] = p[2]; U.u[3] = p[3];
    } else {
#pragma unroll
        for (int t = 0; t < 8; ++t)
            U.s[t] = (d0 + t < DHH) ? row[colbase + d0 + t] : (unsigned short)0;
    }
    return U.v;
}

__global__ __launch_bounds__(256) void attn_kernel(
    const unsigned short* __restrict__ qkv,  // chunk rows x LDQ
    const int* __restrict__ hist_nids,
    unsigned short* __restrict__ mean_ctx,   // BSZ x KP bf16
    int c0)
{
    __shared__ float Sp[2][2][LH][LH];
    __shared__ float P[2][LH][LH];
    __shared__ float pbar[2][LH];
    __shared__ int maskv[LH];
    int b = c0 + blockIdx.x;
    int tid = threadIdx.x;
    int lane = tid & 63, w = tid >> 6;
    int r = lane & 15, q = lane >> 4;
    if (tid < LH) maskv[tid] = (hist_nids[b * LH + tid] == 0 && tid != LH - 1) ? 1 : 0;

    const unsigned short* base = qkv + (size_t)blockIdx.x * LH * LDQ;
    int h = w & 1, kh = w >> 1;
    int qoff = h * DHH;
    int koff = DD + h * DHH;
    f32x4 sacc[2][2] = {};
#pragma unroll
    for (int step = 0; step < 7; ++step) {
        int k0 = kh * 224 + step * 32;
        v8bf16 qf[2], kf[2];
#pragma unroll
        for (int im = 0; im < 2; ++im) {
            int mm = im * 16 + r; if (mm >= LH) mm = LH - 1;
            const unsigned short* rp = base + (size_t)mm * LDQ;
            qf[im] = load_frag(rp, qoff, k0 + q * 8);
            kf[im] = load_frag(rp, koff, k0 + q * 8);
        }
#pragma unroll
        for (int im = 0; im < 2; ++im)
#pragma unroll
            for (int in = 0; in < 2; ++in)
                sacc[im][in] = __builtin_amdgcn_mfma_f32_16x16x32_bf16(
                    qf[im], kf[in], sacc[im][in], 0, 0, 0);
    }
#pragma unroll
    for (int im = 0; im < 2; ++im)
#pragma unroll
        for (int in = 0; in < 2; ++in)
#pragma unroll
            for (int reg = 0; reg < 4; ++reg) {
                int i = im * 16 + q * 4 + reg, jj = in * 16 + r;
                if (i < LH && jj < LH) Sp[h][kh][i][jj] = sacc[im][in][reg];
            }
    __syncthreads();

    if (tid < 2 * LH) {
        int hh = tid / LH, i = tid - (tid / LH) * LH;
        const float scale = 0.0482242822f;  // 1/sqrt(430)
        float s[LH], mx = -1e30f;
#pragma unroll
        for (int jj = 0; jj < LH; ++jj) {
            float v = (Sp[hh][0][i][jj] + Sp[hh][1][i][jj]) * scale;
            if (maskv[jj]) v = -1e30f;
            s[jj] = v; mx = fmaxf(mx, v);
        }
        float sum = 0.f;
#pragma unroll
        for (int jj = 0; jj < LH; ++jj) { float e = expf(s[jj] - mx); s[jj] = e; sum += e; }
        float inv = 1.f / sum;
#pragma unroll
        for (int jj = 0; jj < LH; ++jj) P[hh][i][jj] = s[jj] * inv;
    }
    __syncthreads();
    if (tid < 2 * LH) {
        int hh = tid / LH, jj = tid - (tid / LH) * LH;
        float a = 0.f;
#pragma unroll
        for (int i = 0; i < LH; ++i) a += P[hh][i][jj];
        pbar[hh][jj] = a * (1.f / LH);
    }
    __syncthreads();

    for (int d = tid; d < KP; d += 256) {
        float a = 0.f;
        if (d < DD) {
            int hh = d < DHH ? 0 : 1;
            int dd = d - hh * DHH;
            int voff = 2 * DD + hh * DHH + dd;
#pragma unroll
            for (int jj = 0; jj < LH; ++jj)
                a += pbar[hh][jj] * b2f(base[(size_t)jj * LDQ + voff]);
        }
        mean_ctx[(size_t)b * KP + d] = f2b(a);
    }
}

// ---------------------------------------------------------------------------
extern "C" void kernel_launch(void* const* d_in, const int* in_sizes, int n_in,
                              void* d_out, int out_size, void* d_ws, size_t ws_size,
                              hipStream_t stream)
{
    const int*   nids      = (const int*)d_in[0];
    const int*   hist_nids = (const int*)d_in[1];
    const int*   aids      = (const int*)d_in[2];
    const int*   eids      = (const int*)d_in[3];
    const float* hist_ts   = (const float*)d_in[4];
    const int*   dirs      = (const int*)d_in[5];
    const float* node_emb  = (const float*)d_in[6];
    const float* edge_emb  = (const float*)d_in[7];
    const float* anony_emb = (const float*)d_in[8];
    const float* time_w    = (const float*)d_in[9];
    const float* time_b    = (const float*)d_in[10];
    const float* in_proj_w = (const float*)d_in[11];
    const float* in_proj_b = (const float*)d_in[12];
    const float* out_proj_w= (const float*)d_in[13];
    const float* out_proj_b= (const float*)d_in[14];
    const float* outfn_w   = (const float*)d_in[15];
    const float* outfn_b   = (const float*)d_in[16];
    const float* fc1_w     = (const float*)d_in[17];
    const float* fc1_b     = (const float*)d_in[18];
    const float* fc2_w     = (const float*)d_in[19];
    const float* fc2_b     = (const float*)d_in[20];

    float* out_left  = (float*)d_out;
    float* out_right = out_left + (size_t)BSZ * NFD;
    float* out_ts    = out_right + (size_t)BSZ * NFD;

    char* p = (char*)d_ws;
    auto alloc = [&](size_t bytes) -> char* {
        char* r = p; p += (bytes + 255) & ~(size_t)255; return r;
    };
    unsigned short* Wqkv = (unsigned short*)alloc((size_t)LDQ * KP * 2);
    unsigned short* Wop  = (unsigned short*)alloc((size_t)896 * KP * 2);
    unsigned short* Wofn = (unsigned short*)alloc((size_t)256 * 896 * 2);
    unsigned short* Wfc1 = (unsigned short*)alloc((size_t)256 * KP * 2);
    unsigned short* Wfc2 = (unsigned short*)alloc((size_t)256 * 192 * 2);
    unsigned short* meanctx = (unsigned short*)alloc((size_t)BSZ * KP * 2);
    unsigned short* xbuf    = (unsigned short*)alloc((size_t)BSZ * KP * 2);
    unsigned short* tmp1    = (unsigned short*)alloc((size_t)BSZ * 896 * 2);
    unsigned short* hbuf    = (unsigned short*)alloc((size_t)BSZ * 192 * 2);
    size_t fixed = (size_t)(p - (char*)d_ws);

    int CB = 1024;  // chunk of batch; qkv chunk ~115MB stays L3-resident
    while (CB > 128) {
        size_t need = fixed + (size_t)CB * LH * KP * 2 + (size_t)CB * LH * LDQ * 2 + 4096;
        if (need <= ws_size) break;
        CB >>= 1;
    }
    unsigned short* fullc = (unsigned short*)alloc((size_t)CB * LH * KP * 2);
    unsigned short* qkvc  = (unsigned short*)alloc((size_t)CB * LH * LDQ * 2);

    auto conv = [&](const float* s, unsigned short* d, int N_, int K_, int Np_, int Kp_) {
        int total = Np_ * Kp_;
        int blocks = (total + 255) / 256; if (blocks > 4096) blocks = 4096;
        pad_convert<<<dim3(blocks), dim3(256), 0, stream>>>(s, d, N_, K_, Np_, Kp_);
    };
    conv(in_proj_w,  Wqkv, NQKV, DD, LDQ, KP);
    conv(out_proj_w, Wop,  DD,   DD, 896, KP);
    conv(outfn_w,    Wofn, NFD,  DD, 256, 896);
    conv(fc1_w,      Wfc1, NFD,  DD, 256, KP);
    conv(fc2_w,      Wfc2, NFD,  NFD, 256, 192);

    for (int c0 = 0; c0 < BSZ; c0 += CB) {
        int MB = CB * LH;   // rows this chunk (multiple of 256 for CB>=128)
        build_kernel<<<dim3(CB * LH), dim3(256), 0, stream>>>(
            nids, hist_nids, aids, eids, hist_ts, dirs,
            node_emb, edge_emb, anony_emb, time_w, time_b,
            fullc, xbuf, out_ts, c0);
        gemm_bt_8p<<<dim3(MB / 256, LDQ / 256), dim3(512), 0, stream>>>(
            fullc, Wqkv, in_proj_b, KP, NQKV, qkvc, LDQ);
        attn_kernel<<<dim3(CB), dim3(256), 0, stream>>>(qkvc, hist_nids, meanctx, c0);
    }
    // E1: tmp1 = relu(mean_ctx @ Wop^T + b)   (mean folded through out_proj)
    gemm_bt<<<dim3(BSZ / 128, 7), dim3(256), 0, stream>>>(
        meanctx, Wop, out_proj_b, KP, DD,
        (float*)nullptr, 0, 0, tmp1, 896, 896, 1);
    // E2: h_prev_left = tmp1 @ Wofn^T + b  -> d_out (fp32) and x cols 0..171 (bf16)
    gemm_bt<<<dim3(BSZ / 128, 2), dim3(256), 0, stream>>>(
        tmp1, Wofn, outfn_b, 896, NFD,
        out_left, NFD, NFD, xbuf, KP, NFD, 0);
    // E3: h = relu(x @ Wfc1^T + b) -> bf16 (zero-padded to 192)
    gemm_bt<<<dim3(BSZ / 128, 2), dim3(256), 0, stream>>>(
        xbuf, Wfc1, fc1_b, KP, NFD,
        (float*)nullptr, 0, 0, hbuf, 192, 192, 1);
    // E4: h_prev_right = h @ Wfc2^T + b -> d_out
    gemm_bt<<<dim3(BSZ / 128, 2), dim3(256), 0, stream>>>(
        hbuf, Wfc2, fc2_b, 192, NFD,
        out_right, NFD, NFD, (unsigned short*)nullptr, 0, 0, 0);
}

// Round 2
// 1828.918 us; speedup vs baseline: 1.2502x; 1.1666x over previous
//
#include <hip/hip_runtime.h>

#define BSZ 8192
#define LH 20
#define NFD 172
#define DD 860        // D = 172*4 + 172
#define DHH 430       // D / 2 heads
#define KP 896        // D padded to mult of 64 (8-phase GEMM uses BK=64)
#define NQK 1792      // Q(860)+pad36 | K(860)+pad36  (mult of 256)
#define KOFF 896      // K block starts at col 896 in qkv rows
#define LDQ 1792

typedef float f32x4 __attribute__((ext_vector_type(4)));
typedef __bf16 v8bf16 __attribute__((ext_vector_type(8)));

typedef __attribute__((address_space(3))) void lds_void;
typedef const __attribute__((address_space(1))) void global_void;

static __device__ __forceinline__ unsigned short f2b(float f) {
    union { float f; unsigned u; } U; U.f = f;
    unsigned r = (U.u + 0x7fffu + ((U.u >> 16) & 1u)) >> 16;
    return (unsigned short)r;
}
static __device__ __forceinline__ float b2f(unsigned short x) {
    union { unsigned u; float f; } U; U.u = ((unsigned)x) << 16; return U.f;
}
static __device__ __forceinline__ void async16(const void* g, void* l) {
    __builtin_amdgcn_global_load_lds((global_void*)g, (lds_void*)l, 16, 0, 0);
}

// ---------------------------------------------------------------------------
// Weight convert + zero-pad: src fp32 (N,K) -> dst bf16 (Np,Kp)
// ---------------------------------------------------------------------------
__global__ __launch_bounds__(256) void pad_convert(
    const float* __restrict__ src, unsigned short* __restrict__ dst,
    int N, int K, int Np, int Kp)
{
    int total = Np * Kp;
    for (int i = blockIdx.x * blockDim.x + threadIdx.x; i < total;
         i += gridDim.x * blockDim.x) {
        int n = i / Kp, k = i - (i / Kp) * Kp;
        float v = (n < N && k < K) ? src[(size_t)n * K + k] : 0.f;
        dst[i] = f2b(v);
    }
}

// ---------------------------------------------------------------------------
// Wqk prep: dst [NQK x KP] bf16 from in_proj_w rows [0,1720).
// Row layout: n<860 -> q row n; 896<=n<1756 -> k row (n-36); else zeros.
// ---------------------------------------------------------------------------
__global__ __launch_bounds__(256) void prep_wqk(
    const float* __restrict__ W, unsigned short* __restrict__ dst)
{
    int total = NQK * KP;
    for (int i = blockIdx.x * blockDim.x + threadIdx.x; i < total;
         i += gridDim.x * blockDim.x) {
        int n = i / KP, k = i - (i / KP) * KP;
        float v = 0.f;
        int srow = -1;
        if (n < DD) srow = n;
        else if (n >= KOFF && n < KOFF + DD) srow = DD + (n - KOFF);
        if (srow >= 0 && k < DD) v = W[(size_t)srow * DD + k];
        dst[i] = f2b(v);
    }
}

// ---------------------------------------------------------------------------
// WvcatT prep: Bv [NQK x KP] bf16, Bv[n][d] = Wvcat[d][n] where
// Wvcat[d][n] = in_proj_w[(1720+d)*860 + (n - 896*h(d))] for
// h(d) = (d<430?0:1), 0 <= n-896h < 860; else 0.
// (Used as B in Wfold = Wop @ Wvcat.)
// ---------------------------------------------------------------------------
__global__ __launch_bounds__(256) void prep_wvcatT(
    const float* __restrict__ W, unsigned short* __restrict__ dst)
{
    int total = NQK * KP;
    for (int i = blockIdx.x * blockDim.x + threadIdx.x; i < total;
         i += gridDim.x * blockDim.x) {
        int n = i / KP, d = i - (i / KP) * KP;
        float v = 0.f;
        if (d < DHH) {
            if (n < DD) v = W[(size_t)(2 * DD + d) * DD + n];
        } else if (d < DD) {
            if (n >= KOFF && n < KOFF + DD) v = W[(size_t)(2 * DD + d) * DD + (n - KOFF)];
        }
        dst[i] = f2b(v);
    }
}

// ---------------------------------------------------------------------------
// Small prep: qkbias[NQK] (remapped in_proj_b for q|k layout), zbias[NQK]=0,
// bprime[896] = out_proj_b + Wop @ bv  (bias of the folded E1 GEMM).
// ---------------------------------------------------------------------------
__global__ __launch_bounds__(256) void prep_small(
    const float* __restrict__ in_proj_b, const float* __restrict__ out_proj_w,
    const float* __restrict__ out_proj_b,
    float* __restrict__ qkbias, float* __restrict__ bprime, float* __restrict__ zbias)
{
    int t = threadIdx.x;
    if (blockIdx.x == 0) {
        for (int n = t; n < NQK; n += 256) {
            float v = 0.f;
            if (n < DD) v = in_proj_b[n];
            else if (n >= KOFF && n < KOFF + DD) v = in_proj_b[DD + (n - KOFF)];
            qkbias[n] = v;
            zbias[n] = 0.f;
        }
    }
    int o = blockIdx.x * 256 + t;
    if (o < 896) {
        float a = 0.f;
        if (o < DD) {
            a = out_proj_b[o];
            for (int k2 = 0; k2 < DD; ++k2)
                a += out_proj_w[(size_t)o * DD + k2] * in_proj_b[2 * DD + k2];
        }
        bprime[o] = a;
    }
}

// ---------------------------------------------------------------------------
// Build `full` (chunk rows x KP, bf16), last-event-feat into xbuf cols 172..,
// prev_ts output. One block per (b,j) row.
// ---------------------------------------------------------------------------
__global__ __launch_bounds__(256) void build_kernel(
    const int* __restrict__ nids, const int* __restrict__ hist_nids,
    const int* __restrict__ aids, const int* __restrict__ eids,
    const float* __restrict__ ts, const int* __restrict__ dirs,
    const float* __restrict__ node_emb, const float* __restrict__ edge_emb,
    const float* __restrict__ anony_emb, const float* __restrict__ time_w,
    const float* __restrict__ time_b,
    unsigned short* __restrict__ full, unsigned short* __restrict__ xbuf,
    float* __restrict__ prev_ts, int c0)
{
    int idx = blockIdx.x;
    int b = c0 + idx / LH;
    int j = idx - (idx / LH) * LH;
    int nid = nids[b];
    int hn  = hist_nids[b * LH + j];
    int dir = dirs[b * LH + j];
    int src = dir ? nid : hn;
    int dst = dir ? hn : nid;
    int aid = aids[b * LH + j];
    int eid = eids[b * LH + j];
    float tlast = ts[b * LH + (LH - 1)];
    float dt = tlast - ts[b * LH + j];
    bool last = (j == LH - 1);
    unsigned short* frow = full + (size_t)idx * KP;

    for (int c = threadIdx.x; c < KP; c += blockDim.x) {
        float v;
        if (c < NFD)            v = node_emb[(size_t)src * NFD + c];
        else if (c < 2 * NFD)   v = node_emb[(size_t)dst * NFD + (c - NFD)];
        else if (c < 3 * NFD)   v = anony_emb[(size_t)aid * NFD + (c - 2 * NFD)];
        else if (c < 4 * NFD)   v = edge_emb[(size_t)eid * NFD + (c - 3 * NFD)];
        else if (c < DD) { int tf = c - 4 * NFD; v = cosf(dt * time_w[tf] + time_b[tf]); }
        else                    v = 0.f;
        unsigned short bv = f2b(v);
        if (last) {
            if (c < 4 * NFD) {
                // last_event_feat -> x cols [172, 860); zero the full row entry
                xbuf[(size_t)b * KP + NFD + c] = bv;
                frow[c] = 0;
            } else {
                frow[c] = bv;
                // zero x pad cols [860, KP): c in [688, 688+36)
                if (c < 4 * NFD + 36) xbuf[(size_t)b * KP + NFD + c] = 0;
            }
        } else {
            frow[c] = bv;
        }
    }
    if (last && threadIdx.x == 0) prev_ts[b] = tlast;
}

// ---------------------------------------------------------------------------
// bf16 MFMA GEMM: C[M,N] = A[M,Kp] @ B[N,Kp]^T (+bias, opt relu)
// m97 structure: 128x128 tile, BK=32, 4 waves. For small/odd-shape GEMMs.
// ---------------------------------------------------------------------------
__global__ __launch_bounds__(256) void gemm_bt(
    const unsigned short* __restrict__ A, const unsigned short* __restrict__ B,
    const float* __restrict__ bias, int Kp, int N,
    float* __restrict__ outF, int ldF, int nF,
    unsigned short* __restrict__ outB, int ldB, int nB, int relu)
{
    __shared__ __align__(16) unsigned short As[128 * 32];
    __shared__ __align__(16) unsigned short Bs[128 * 32];
    int tid = threadIdx.x;
    int w = tid >> 6, lane = tid & 63;
    int r = lane & 15, q = lane >> 4;
    int m0 = blockIdx.x * 128;
    int n0 = blockIdx.y * 128;
    int wm = (w >> 1) * 64, wn = (w & 1) * 64;
    f32x4 acc[4][4] = {};
    int ktiles = Kp >> 5;

    for (int kt = 0; kt < ktiles; ++kt) {
        int k0 = kt * 32;
#pragma unroll
        for (int iss = 0; iss < 2; ++iss) {
            int chunk = iss * 256 + w * 64 + lane;       // 0..511
            int mm = chunk >> 2, kc = chunk & 3;
            const unsigned short* ga = A + (size_t)(m0 + mm) * Kp + k0 + kc * 8;
            async16(ga, &As[(size_t)(iss * 256 + w * 64) * 8]);
            const unsigned short* gb = B + (size_t)(n0 + mm) * Kp + k0 + kc * 8;
            async16(gb, &Bs[(size_t)(iss * 256 + w * 64) * 8]);
        }
        __syncthreads();
        v8bf16 af[4], bfr[4];
#pragma unroll
        for (int im = 0; im < 4; ++im)
            af[im] = *(const v8bf16*)&As[(wm + im * 16 + r) * 32 + q * 8];
#pragma unroll
        for (int in = 0; in < 4; ++in)
            bfr[in] = *(const v8bf16*)&Bs[(wn + in * 16 + r) * 32 + q * 8];
#pragma unroll
        for (int im = 0; im < 4; ++im)
#pragma unroll
            for (int in = 0; in < 4; ++in)
                acc[im][in] = __builtin_amdgcn_mfma_f32_16x16x32_bf16(
                    af[im], bfr[in], acc[im][in], 0, 0, 0);
        __syncthreads();
    }

#pragma unroll
    for (int im = 0; im < 4; ++im) {
        int rowb = m0 + wm + im * 16 + q * 4;
#pragma unroll
        for (int in = 0; in < 4; ++in) {
            int col = n0 + wn + in * 16 + r;
            float bv = (col < N) ? bias[col] : 0.f;
#pragma unroll
            for (int reg = 0; reg < 4; ++reg) {
                float v = acc[im][in][reg];
                if (col < N) { v += bv; if (relu) v = fmaxf(v, 0.f); }
                else v = 0.f;
                int rr = rowb + reg;
                if (outF && col < nF) outF[(size_t)rr * ldF + col] = v;
                if (outB && col < nB) outB[(size_t)rr * ldB + col] = f2b(v);
            }
        }
    }
}

// ---------------------------------------------------------------------------
// 256x256 / BK=64 / 8-wave / 8-phase counted-vmcnt GEMM (T2+T3+T4+T5).
// Work remap: 7 consecutive work-ids share one A-tile (n varies fastest) and
// ids are chunked per-XCD (bijective, requires nwg%8==0) so the A-tile is
// L2-resident across its 7 uses; B (3.2 MB) stays L2-resident per XCD.
// ---------------------------------------------------------------------------
static __device__ __forceinline__ v8bf16 lds_frag256(
    const unsigned short* t /*256x64 tile*/, int row, int colB /*bytes*/)
{
    int o = row * 128 + (colB ^ (((row >> 2) & 1) << 5));
    return *(const v8bf16*)((const char*)t + o);
}

static __device__ __forceinline__ void stage_half(
    const unsigned short* __restrict__ G, int rowBase, int Kp, int kt,
    unsigned short* lh /*&lds[buf][op][half][0]*/, int w, int lane)
{
#pragma unroll
    for (int l = 0; l < 2; ++l) {
        int rowInHalf = l * 64 + w * 8 + (lane >> 3);
        // inverse-swizzled source column (bit5 of byte col XOR'd with dest bit9)
        int colE = (((lane & 7) * 16) ^ ((lane >> 5) << 5)) >> 1;
        const unsigned short* g =
            G + (size_t)(rowBase + rowInHalf) * Kp + kt * 64 + colE;
        async16(g, lh + l * 4096 + w * 512);   // HW adds lane*16 bytes
    }
}

__global__ __launch_bounds__(512, 2) void gemm_bt_8p(
    const unsigned short* __restrict__ A, const unsigned short* __restrict__ B,
    const float* __restrict__ bias, int Kp, int N,
    unsigned short* __restrict__ outB, int ldB)
{
    __shared__ __align__(16) unsigned short lds[2][2][2][128 * 64];
    const int tid = threadIdx.x;
    const int w = tid >> 6, lane = tid & 63;
    const int r = lane & 15, q = lane >> 4;

    // ---- work remap: XCD-chunked, n-fastest within an m-tile ----
    int d = blockIdx.y * gridDim.x + blockIdx.x;
    int nwg = gridDim.x * gridDim.y;
    int wrk = ((nwg & 7) == 0) ? ((d & 7) * (nwg >> 3) + (d >> 3)) : d;
    int ny = gridDim.y;
    int mt = wrk / ny, ntl = wrk - mt * ny;
    const int m0 = mt * 256;
    const int n0 = ntl * 256;

    const int wm = (w >> 2) * 128, wn = (w & 3) * 64;
    const int nt = Kp >> 6;        // K-tiles of 64
    const int niter = nt >> 1;     // 2 K-tiles per iteration

    f32x4 acc[8][4] = {};

    // prologue: stage A0,B0 (8 loads) + B1 (4 loads); wait A0,B0; B1 in flight
    stage_half(A, m0 + 0,   Kp, 0, &lds[0][0][0][0], w, lane);
    stage_half(A, m0 + 128, Kp, 0, &lds[0][0][1][0], w, lane);
    stage_half(B, n0 + 0,   Kp, 0, &lds[0][1][0][0], w, lane);
    stage_half(B, n0 + 128, Kp, 0, &lds[0][1][1][0], w, lane);
    stage_half(B, n0 + 0,   Kp, 1, &lds[1][1][0][0], w, lane);
    stage_half(B, n0 + 128, Kp, 1, &lds[1][1][1][0], w, lane);
    asm volatile("s_waitcnt vmcnt(4)");
    __builtin_amdgcn_sched_barrier(0);
    __builtin_amdgcn_s_barrier();

    for (int i = 0; i < niter; ++i) {
        const int T = 2 * i;
        const bool notLast = (i + 1 < niter);
#pragma unroll
        for (int tt = 0; tt < 2; ++tt) {               // tile T+tt in buf tt
            const unsigned short* At = &lds[tt][0][0][0];
            const unsigned short* Bt = &lds[tt][1][0][0];
            v8bf16 bf[4][2];
#pragma unroll
            for (int mp = 0; mp < 4; ++mp) {           // phase = tt*4 + mp + 1
                if (mp == 0) {
#pragma unroll
                    for (int in = 0; in < 4; ++in)
#pragma unroll
                        for (int kk = 0; kk < 2; ++kk)
                            bf[in][kk] = lds_frag256(Bt, wn + in * 16 + r,
                                                     kk * 64 + q * 16);
                }
                v8bf16 a0[2], a1[2];
#pragma unroll
                for (int kk = 0; kk < 2; ++kk) {
                    a0[kk] = lds_frag256(At, wm + (mp * 2 + 0) * 16 + r,
                                         kk * 64 + q * 16);
                    a1[kk] = lds_frag256(At, wm + (mp * 2 + 1) * 16 + r,
                                         kk * 64 + q * 16);
                }
                // staging schedule (each target region fully consumed >=1
                // barrier before its overwrite is issued):
                if (tt == 0 && mp == 0)
                    stage_half(A, m0 + 0,   Kp, T + 1, &lds[1][0][0][0], w, lane);
                if (tt == 0 && mp == 1) {
                    stage_half(A, m0 + 128, Kp, T + 1, &lds[1][0][1][0], w, lane);
                    if (notLast)
                        stage_half(B, n0 + 0,   Kp, T + 2, &lds[0][1][0][0], w, lane);
                }
                if (tt == 0 && mp == 2 && notLast)
                    stage_half(B, n0 + 128, Kp, T + 2, &lds[0][1][1][0], w, lane);
                if (tt == 1 && mp == 0 && notLast)
                    stage_half(A, m0 + 0,   Kp, T + 2, &lds[0][0][0][0], w, lane);
                if (tt == 1 && mp == 1 && notLast)
                    stage_half(A, m0 + 128, Kp, T + 2, &lds[0][0][1][0], w, lane);
                if (tt == 1 && mp == 2 && notLast)
                    stage_half(B, n0 + 0,   Kp, T + 3, &lds[1][1][0][0], w, lane);
                if (tt == 1 && mp == 3 && notLast)
                    stage_half(B, n0 + 128, Kp, T + 3, &lds[1][1][1][0], w, lane);

                if (mp == 3) {
                    if (notLast) {
                        asm volatile("s_waitcnt vmcnt(4)");   // keep next B in flight
                    } else if (tt == 0) {
                        asm volatile("s_waitcnt vmcnt(0)");   // drain for last tile
                    }
                    __builtin_amdgcn_sched_barrier(0);
                }
                __builtin_amdgcn_s_barrier();
                asm volatile("s_waitcnt lgkmcnt(0)");
                __builtin_amdgcn_sched_barrier(0);
                __builtin_amdgcn_s_setprio(1);
#pragma unroll
                for (int kk = 0; kk < 2; ++kk)
#pragma unroll
                    for (int in = 0; in < 4; ++in) {
                        acc[mp * 2 + 0][in] = __builtin_amdgcn_mfma_f32_16x16x32_bf16(
                            a0[kk], bf[in][kk], acc[mp * 2 + 0][in], 0, 0, 0);
                        acc[mp * 2 + 1][in] = __builtin_amdgcn_mfma_f32_16x16x32_bf16(
                            a1[kk], bf[in][kk], acc[mp * 2 + 1][in], 0, 0, 0);
                    }
                __builtin_amdgcn_s_setprio(0);
                __builtin_amdgcn_s_barrier();
            }
        }
    }

#pragma unroll
    for (int im = 0; im < 8; ++im) {
        int rowb = m0 + wm + im * 16 + q * 4;
#pragma unroll
        for (int in = 0; in < 4; ++in) {
            int col = n0 + wn + in * 16 + r;
            float bv = (col < N) ? bias[col] : 0.f;
#pragma unroll
            for (int reg = 0; reg < 4; ++reg) {
                float v = (col < N) ? acc[im][in][reg] + bv : 0.f;
                outB[(size_t)(rowb + reg) * ldB + col] = f2b(v);
            }
        }
    }
}

// ---------------------------------------------------------------------------
// Attention per b: S=QK^T via MFMA, softmax w/ mask, pbar_h = mean_i P_h.
// Output: fbar[b] = [ sum_j pbar0[j]*full[j] (KP) | sum_j pbar1[j]*full[j] (KP) ]
// (V- and out-projections are folded into the downstream Wfold GEMM.)
// ---------------------------------------------------------------------------
static __device__ __forceinline__ v8bf16 load_frag(
    const unsigned short* row, int colbase, int d0)
{
    union { unsigned u[4]; v8bf16 v; unsigned short s[8]; } U;
    if (d0 + 8 <= DHH) {
        const unsigned* p = (const unsigned*)(row + colbase + d0);
        U.u[0] = p[0]; U.u[1] = p[1]; U.u[2] = p[2]; U.u[3] = p[3];
    } else {
#pragma unroll
        for (int t = 0; t < 8; ++t)
            U.s[t] = (d0 + t < DHH) ? row[colbase + d0 + t] : (unsigned short)0;
    }
    return U.v;
}

__global__ __launch_bounds__(256) void attn_kernel(
    const unsigned short* __restrict__ qkv,   // chunk rows x LDQ (q|k)
    const unsigned short* __restrict__ fullr, // chunk rows x KP
    const int* __restrict__ hist_nids,
    unsigned short* __restrict__ fbar,        // BSZ x 2*KP bf16
    int c0)
{
    __shared__ float Sp[2][2][LH][LH];
    __shared__ float P[2][LH][LH];
    __shared__ float pbar[2][LH];
    __shared__ int maskv[LH];
    int b = c0 + blockIdx.x;
    int tid = threadIdx.x;
    int lane = tid & 63, w = tid >> 6;
    int r = lane & 15, q = lane >> 4;
    if (tid < LH) maskv[tid] = (hist_nids[b * LH + tid] == 0 && tid != LH - 1) ? 1 : 0;

    const unsigned short* base = qkv + (size_t)blockIdx.x * LH * LDQ;
    int h = w & 1, kh = w >> 1;
    int qoff = h * DHH;
    int koff = KOFF + h * DHH;
    f32x4 sacc[2][2] = {};
#pragma unroll
    for (int step = 0; step < 7; ++step) {
        int k0 = kh * 224 + step * 32;
        v8bf16 qf[2], kf[2];
#pragma unroll
        for (int im = 0; im < 2; ++im) {
            int mm = im * 16 + r; if (mm >= LH) mm = LH - 1;
            const unsigned short* rp = base + (size_t)mm * LDQ;
            qf[im] = load_frag(rp, qoff, k0 + q * 8);
            kf[im] = load_frag(rp, koff, k0 + q * 8);
        }
#pragma unroll
        for (int im = 0; im < 2; ++im)
#pragma unroll
            for (int in = 0; in < 2; ++in)
                sacc[im][in] = __builtin_amdgcn_mfma_f32_16x16x32_bf16(
                    qf[im], kf[in], sacc[im][in], 0, 0, 0);
    }
#pragma unroll
    for (int im = 0; im < 2; ++im)
#pragma unroll
        for (int in = 0; in < 2; ++in)
#pragma unroll
            for (int reg = 0; reg < 4; ++reg) {
                int i = im * 16 + q * 4 + reg, jj = in * 16 + r;
                if (i < LH && jj < LH) Sp[h][kh][i][jj] = sacc[im][in][reg];
            }
    __syncthreads();

    if (tid < 2 * LH) {
        int hh = tid / LH, i = tid - (tid / LH) * LH;
        const float scale = 0.0482242822f;  // 1/sqrt(430)
        float s[LH], mx = -1e30f;
#pragma unroll
        for (int jj = 0; jj < LH; ++jj) {
            float v = (Sp[hh][0][i][jj] + Sp[hh][1][i][jj]) * scale;
            if (maskv[jj]) v = -1e30f;
            s[jj] = v; mx = fmaxf(mx, v);
        }
        float sum = 0.f;
#pragma unroll
        for (int jj = 0; jj < LH; ++jj) { float e = expf(s[jj] - mx); s[jj] = e; sum += e; }
        float inv = 1.f / sum;
#pragma unroll
        for (int jj = 0; jj < LH; ++jj) P[hh][i][jj] = s[jj] * inv;
    }
    __syncthreads();
    if (tid < 2 * LH) {
        int hh = tid / LH, jj = tid - (tid / LH) * LH;
        float a = 0.f;
#pragma unroll
        for (int i = 0; i < LH; ++i) a += P[hh][i][jj];
        pbar[hh][jj] = a * (1.f / LH);
    }
    __syncthreads();

    const unsigned short* fb = fullr + (size_t)blockIdx.x * LH * KP;
    for (int k = tid; k < KP; k += 256) {
        float a0 = 0.f, a1 = 0.f;
#pragma unroll
        for (int jj = 0; jj < LH; ++jj) {
            float v = b2f(fb[(size_t)jj * KP + k]);
            a0 += pbar[0][jj] * v;
            a1 += pbar[1][jj] * v;
        }
        fbar[(size_t)b * (2 * KP) + k]      = f2b(a0);
        fbar[(size_t)b * (2 * KP) + KP + k] = f2b(a1);
    }
}

// ---------------------------------------------------------------------------
extern "C" void kernel_launch(void* const* d_in, const int* in_sizes, int n_in,
                              void* d_out, int out_size, void* d_ws, size_t ws_size,
                              hipStream_t stream)
{
    const int*   nids      = (const int*)d_in[0];
    const int*   hist_nids = (const int*)d_in[1];
    const int*   aids      = (const int*)d_in[2];
    const int*   eids      = (const int*)d_in[3];
    const float* hist_ts   = (const float*)d_in[4];
    const int*   dirs      = (const int*)d_in[5];
    const float* node_emb  = (const float*)d_in[6];
    const float* edge_emb  = (const float*)d_in[7];
    const float* anony_emb = (const float*)d_in[8];
    const float* time_w    = (const float*)d_in[9];
    const float* time_b    = (const float*)d_in[10];
    const float* in_proj_w = (const float*)d_in[11];
    const float* in_proj_b = (const float*)d_in[12];
    const float* out_proj_w= (const float*)d_in[13];
    const float* out_proj_b= (const float*)d_in[14];
    const float* outfn_w   = (const float*)d_in[15];
    const float* outfn_b   = (const float*)d_in[16];
    const float* fc1_w     = (const float*)d_in[17];
    const float* fc1_b     = (const float*)d_in[18];
    const float* fc2_w     = (const float*)d_in[19];
    const float* fc2_b     = (const float*)d_in[20];

    float* out_left  = (float*)d_out;
    float* out_right = out_left + (size_t)BSZ * NFD;
    float* out_ts    = out_right + (size_t)BSZ * NFD;

    char* p = (char*)d_ws;
    auto alloc = [&](size_t bytes) -> char* {
        char* r = p; p += (bytes + 255) & ~(size_t)255; return r;
    };
    unsigned short* Wqk  = (unsigned short*)alloc((size_t)NQK * KP * 2);
    unsigned short* Bv   = (unsigned short*)alloc((size_t)NQK * KP * 2);
    unsigned short* Wfold= (unsigned short*)alloc((size_t)896 * NQK * 2);
    unsigned short* Wop  = (unsigned short*)alloc((size_t)896 * KP * 2);
    unsigned short* Wofn = (unsigned short*)alloc((size_t)256 * 896 * 2);
    unsigned short* Wfc1 = (unsigned short*)alloc((size_t)256 * KP * 2);
    unsigned short* Wfc2 = (unsigned short*)alloc((size_t)256 * 192 * 2);
    float* qkbias = (float*)alloc((size_t)NQK * 4);
    float* bprime = (float*)alloc((size_t)896 * 4);
    float* zbias  = (float*)alloc((size_t)NQK * 4);
    unsigned short* fbarb = (unsigned short*)alloc((size_t)BSZ * 2 * KP * 2);
    unsigned short* xbuf  = (unsigned short*)alloc((size_t)BSZ * KP * 2);
    unsigned short* tmp1  = (unsigned short*)alloc((size_t)BSZ * 896 * 2);
    unsigned short* hbuf  = (unsigned short*)alloc((size_t)BSZ * 192 * 2);
    size_t fixed = (size_t)(p - (char*)d_ws);

    int CB = 2048;  // chunk of batch; full+qkv chunk ~220MB stays L3-resident
    while (CB > 128) {
        size_t need = fixed + (size_t)CB * LH * KP * 2 + (size_t)CB * LH * LDQ * 2 + 4096;
        if (need <= ws_size) break;
        CB >>= 1;
    }
    unsigned short* fullc = (unsigned short*)alloc((size_t)CB * LH * KP * 2);
    unsigned short* qkvc  = (unsigned short*)alloc((size_t)CB * LH * LDQ * 2);

    auto conv = [&](const float* s, unsigned short* d, int N_, int K_, int Np_, int Kp_) {
        int total = Np_ * Kp_;
        int blocks = (total + 255) / 256; if (blocks > 4096) blocks = 4096;
        pad_convert<<<dim3(blocks), dim3(256), 0, stream>>>(s, d, N_, K_, Np_, Kp_);
    };
    {
        int blocks = (NQK * KP + 255) / 256; if (blocks > 4096) blocks = 4096;
        prep_wqk<<<dim3(blocks), dim3(256), 0, stream>>>(in_proj_w, Wqk);
        prep_wvcatT<<<dim3(blocks), dim3(256), 0, stream>>>(in_proj_w, Bv);
    }
    conv(out_proj_w, Wop,  DD,   DD, 896, KP);
    conv(outfn_w,    Wofn, NFD,  DD, 256, 896);
    conv(fc1_w,      Wfc1, NFD,  DD, 256, KP);
    conv(fc2_w,      Wfc2, NFD,  NFD, 256, 192);
    prep_small<<<dim3(4), dim3(256), 0, stream>>>(
        in_proj_b, out_proj_w, out_proj_b, qkbias, bprime, zbias);
    // Wfold[896 x NQK] = Wop @ Wvcat   (A=Wop bf16, B=Bv, K=896)
    gemm_bt<<<dim3(896 / 128, NQK / 128), dim3(256), 0, stream>>>(
        Wop, Bv, zbias, KP, NQK,
        (float*)nullptr, 0, 0, Wfold, NQK, NQK, 0);

    for (int c0 = 0; c0 < BSZ; c0 += CB) {
        build_kernel<<<dim3(CB * LH), dim3(256), 0, stream>>>(
            nids, hist_nids, aids, eids, hist_ts, dirs,
            node_emb, edge_emb, anony_emb, time_w, time_b,
            fullc, xbuf, out_ts, c0);
        gemm_bt_8p<<<dim3(CB * LH / 256, NQK / 256), dim3(512), 0, stream>>>(
            fullc, Wqk, qkbias, KP, NQK, qkvc, LDQ);
        attn_kernel<<<dim3(CB), dim3(256), 0, stream>>>(
            qkvc, fullc, hist_nids, fbarb, c0);
    }
    // E1 (folded): tmp1 = relu(fbar @ Wfold^T + bprime), K=1792
    gemm_bt<<<dim3(BSZ / 128, 7), dim3(256), 0, stream>>>(
        fbarb, Wfold, bprime, NQK, DD,
        (float*)nullptr, 0, 0, tmp1, 896, 896, 1);
    // E2: h_prev_left = tmp1 @ Wofn^T + b  -> d_out (fp32) and x cols 0..171 (bf16)
    gemm_bt<<<dim3(BSZ / 128, 2), dim3(256), 0, stream>>>(
        tmp1, Wofn, outfn_b, 896, NFD,
        out_left, NFD, NFD, xbuf, KP, NFD, 0);
    // E3: h = relu(x @ Wfc1^T + b) -> bf16 (zero-padded to 192)
    gemm_bt<<<dim3(BSZ / 128, 2), dim3(256), 0, stream>>>(
        xbuf, Wfc1, fc1_b, KP, NFD,
        (float*)nullptr, 0, 0, hbuf, 192, 192, 1);
    // E4: h_prev_right = h @ Wfc2^T + b -> d_out
    gemm_bt<<<dim3(BSZ / 128, 2), dim3(256), 0, stream>>>(
        hbuf, Wfc2, fc2_b, 192, NFD,
        out_right, NFD, NFD, (unsigned short*)nullptr, 0, 0, 0);
}

// Round 3
// 1692.689 us; speedup vs baseline: 1.3508x; 1.0805x over previous
//
#include <hip/hip_runtime.h>

#define BSZ 8192
#define LH 20
#define NFD 172
#define DD 860        // D = 172*4 + 172
#define DHH 430       // D / 2 heads
#define KP 896        // D padded to mult of 64 (8-phase GEMM uses BK=64)
#define NQK 1792      // Q(860)+pad36 | K(860)+pad36  (mult of 256)
#define KOFF 896      // K block starts at col 896 in qkv rows
#define LDQ 1792

typedef float f32x4 __attribute__((ext_vector_type(4)));
typedef __bf16 v8bf16 __attribute__((ext_vector_type(8)));
typedef unsigned short u16x4 __attribute__((ext_vector_type(4)));

typedef __attribute__((address_space(3))) void lds_void;
typedef const __attribute__((address_space(1))) void global_void;

static __device__ __forceinline__ unsigned short f2b(float f) {
    union { float f; unsigned u; } U; U.f = f;
    unsigned r = (U.u + 0x7fffu + ((U.u >> 16) & 1u)) >> 16;
    return (unsigned short)r;
}
static __device__ __forceinline__ float b2f(unsigned short x) {
    union { unsigned u; float f; } U; U.u = ((unsigned)x) << 16; return U.f;
}
static __device__ __forceinline__ void async16(const void* g, void* l) {
    __builtin_amdgcn_global_load_lds((global_void*)g, (lds_void*)l, 16, 0, 0);
}
static __device__ __forceinline__ u16x4 pack4(float4 v) {
    u16x4 o; o.x = f2b(v.x); o.y = f2b(v.y); o.z = f2b(v.z); o.w = f2b(v.w);
    return o;
}

// ---------------------------------------------------------------------------
// prep_all: ONE kernel for all weight preps (was 8 launches).
// Segments by blockIdx.x:
//   [0,1568)      Wqk   [NQK x KP]   (q|k row remap of in_proj_w, bf16)
//   [1568,3136)   Bv    [NQK x KP]   (transposed Wv for the fold GEMM)
//   [3136,3920)   Wop   conv 860x860 -> 896x896
//   [3920,4144)   Wofn  conv 172x860 -> 256x896
//   [4144,4368)   Wfc1  conv 172x860 -> 256x896
//   [4368,4416)   Wfc2  conv 172x172 -> 256x192
//   [4416,4418)   qkbias/zbias
//   [4418,4642)   bprime (wave-parallel: one wave per output o)
// ---------------------------------------------------------------------------
#define B_WQK   1568
#define B_BV    1568
#define B_WOP   784
#define B_WOFN  224
#define B_WFC1  224
#define B_WFC2  48
#define B_BIAS  2
#define B_BPR   224
#define PREP_BLOCKS (B_WQK + B_BV + B_WOP + B_WOFN + B_WFC1 + B_WFC2 + B_BIAS + B_BPR)

static __device__ __forceinline__ void conv4(
    const float* __restrict__ src, unsigned short* __restrict__ dst,
    int N, int K, int Kp, int vecid)
{
    int i = vecid * 4;
    int n = i / Kp, k = i - (i / Kp) * Kp;   // k mult of 4 (Kp mult of 4)
    u16x4 o;
    if (n < N && k + 3 < K) {                // K mult of 4 for all our tables
        o = pack4(*(const float4*)&src[(size_t)n * K + k]);
    } else {
        float a[4];
#pragma unroll
        for (int t = 0; t < 4; ++t)
            a[t] = (n < N && k + t < K) ? src[(size_t)n * K + k + t] : 0.f;
        o.x = f2b(a[0]); o.y = f2b(a[1]); o.z = f2b(a[2]); o.w = f2b(a[3]);
    }
    *(u16x4*)&dst[i] = o;
}

__global__ __launch_bounds__(256) void prep_all(
    const float* __restrict__ in_proj_w, const float* __restrict__ out_proj_w,
    const float* __restrict__ outfn_w, const float* __restrict__ fc1_w,
    const float* __restrict__ fc2_w, const float* __restrict__ in_proj_b,
    const float* __restrict__ out_proj_b,
    unsigned short* __restrict__ Wqk, unsigned short* __restrict__ Bv,
    unsigned short* __restrict__ Wop, unsigned short* __restrict__ Wofn,
    unsigned short* __restrict__ Wfc1, unsigned short* __restrict__ Wfc2,
    float* __restrict__ qkbias, float* __restrict__ zbias,
    float* __restrict__ bprime)
{
    int bid = blockIdx.x, tid = threadIdx.x;
    if (bid < B_WQK) {
        // Wqk: rows n<860 -> q row n; rows [896,1756) -> k row n-36; else 0
        int i = (bid * 256 + tid) * 4;
        int n = i / KP, k = i - (i / KP) * KP;
        int srow = -1;
        if (n < DD) srow = n;
        else if (n >= KOFF && n < KOFF + DD) srow = DD + (n - KOFF);
        u16x4 o = {0, 0, 0, 0};
        if (srow >= 0 && k < DD)   // k mult of 4, k<860 => k+3<=859
            o = pack4(*(const float4*)&in_proj_w[(size_t)srow * DD + k]);
        *(u16x4*)&Wqk[i] = o;
        return;
    }
    bid -= B_WQK;
    if (bid < B_BV) {
        // Bv[n][d] = Wvcat[d][n]  (transpose; strided scalar reads, L2-served)
        int i = (bid * 256 + tid) * 4;
        int n = i / KP, d0 = i - (i / KP) * KP;
        u16x4 o;
#pragma unroll
        for (int e = 0; e < 4; ++e) {
            int d = d0 + e;
            float v = 0.f;
            if (d < DHH) {
                if (n < DD) v = in_proj_w[(size_t)(2 * DD + d) * DD + n];
            } else if (d < DD) {
                if (n >= KOFF && n < KOFF + DD)
                    v = in_proj_w[(size_t)(2 * DD + d) * DD + (n - KOFF)];
            }
            ((unsigned short*)&o)[e] = f2b(v);
        }
        *(u16x4*)&Bv[i] = o;
        return;
    }
    bid -= B_BV;
    if (bid < B_WOP)  { conv4(out_proj_w, Wop,  DD,  DD,  KP,  bid * 256 + tid); return; }
    bid -= B_WOP;
    if (bid < B_WOFN) { conv4(outfn_w,    Wofn, NFD, DD,  KP,  bid * 256 + tid); return; }
    bid -= B_WOFN;
    if (bid < B_WFC1) { conv4(fc1_w,      Wfc1, NFD, DD,  KP,  bid * 256 + tid); return; }
    bid -= B_WFC1;
    if (bid < B_WFC2) { conv4(fc2_w,      Wfc2, NFD, NFD, 192, bid * 256 + tid); return; }
    bid -= B_WFC2;
    if (bid < B_BIAS) {
        for (int n = bid * 256 + tid; n < NQK; n += B_BIAS * 256) {
            float v = 0.f;
            if (n < DD) v = in_proj_b[n];
            else if (n >= KOFF && n < KOFF + DD) v = in_proj_b[DD + (n - KOFF)];
            qkbias[n] = v;
            zbias[n] = 0.f;
        }
        return;
    }
    bid -= B_BIAS;
    {   // bprime[o] = out_proj_b[o] + dot(out_proj_w[o,:], bv)  — one wave per o
        int o = bid * 4 + (tid >> 6);
        int lane = tid & 63;
        if (o < DD) {
            float a = 0.f;
            for (int k2 = lane; k2 < DD; k2 += 64)
                a += out_proj_w[(size_t)o * DD + k2] * in_proj_b[2 * DD + k2];
#pragma unroll
            for (int off = 32; off > 0; off >>= 1) a += __shfl_down(a, off, 64);
            if (lane == 0) bprime[o] = out_proj_b[o] + a;
        } else if (o < 896) {
            if (lane == 0) bprime[o] = 0.f;
        }
    }
}

// ---------------------------------------------------------------------------
// Build `full` (chunk rows x KP, bf16), vectorized: thread t handles cols
// [4t,4t+4). All segment boundaries (172/344/516/688/860/896) are mult of 4,
// so a 4-wide chunk never straddles segments. float4 gathers + u16x4 stores.
// ---------------------------------------------------------------------------
__global__ __launch_bounds__(256) void build_kernel(
    const int* __restrict__ nids, const int* __restrict__ hist_nids,
    const int* __restrict__ aids, const int* __restrict__ eids,
    const float* __restrict__ ts, const int* __restrict__ dirs,
    const float* __restrict__ node_emb, const float* __restrict__ edge_emb,
    const float* __restrict__ anony_emb, const float* __restrict__ time_w,
    const float* __restrict__ time_b,
    unsigned short* __restrict__ full, unsigned short* __restrict__ xbuf,
    float* __restrict__ prev_ts, int c0)
{
    int idx = blockIdx.x;
    int b = c0 + idx / LH;
    int j = idx - (idx / LH) * LH;
    int nid = nids[b];
    int hn  = hist_nids[b * LH + j];
    int dir = dirs[b * LH + j];
    int src = dir ? nid : hn;
    int dst = dir ? hn : nid;
    int aid = aids[b * LH + j];
    int eid = eids[b * LH + j];
    float tlast = ts[b * LH + (LH - 1)];
    float dt = tlast - ts[b * LH + j];
    bool last = (j == LH - 1);
    unsigned short* frow = full + (size_t)idx * KP;
    int t = threadIdx.x;
    if (last && t == 0) prev_ts[b] = tlast;
    if (t >= KP / 4) return;
    int c = t * 4;

    float4 v;
    if (c < NFD)            v = *(const float4*)&node_emb[(size_t)src * NFD + c];
    else if (c < 2 * NFD)   v = *(const float4*)&node_emb[(size_t)dst * NFD + (c - NFD)];
    else if (c < 3 * NFD)   v = *(const float4*)&anony_emb[(size_t)aid * NFD + (c - 2 * NFD)];
    else if (c < 4 * NFD)   v = *(const float4*)&edge_emb[(size_t)eid * NFD + (c - 3 * NFD)];
    else if (c < DD) {
        int tf = c - 4 * NFD;
        float4 w = *(const float4*)&time_w[tf];
        float4 bb = *(const float4*)&time_b[tf];
        v.x = cosf(dt * w.x + bb.x); v.y = cosf(dt * w.y + bb.y);
        v.z = cosf(dt * w.z + bb.z); v.w = cosf(dt * w.w + bb.w);
    } else v = make_float4(0.f, 0.f, 0.f, 0.f);

    u16x4 bv = pack4(v);
    const u16x4 z4 = {0, 0, 0, 0};
    if (last) {
        if (c < 4 * NFD) {
            *(u16x4*)&xbuf[(size_t)b * KP + NFD + c] = bv;   // last_event_feat
            *(u16x4*)&frow[c] = z4;
        } else {
            *(u16x4*)&frow[c] = bv;
            if (c < 4 * NFD + 36)                            // x pad cols [860,896)
                *(u16x4*)&xbuf[(size_t)b * KP + NFD + c] = z4;
        }
    } else {
        *(u16x4*)&frow[c] = bv;
    }
}

// ---------------------------------------------------------------------------
// bf16 MFMA GEMM: C[M,N] = A[M,Kp] @ B[N,Kp]^T (+bias, opt relu)
// m97 structure: 128x128 tile, BK=32, 4 waves. For small/odd-shape GEMMs.
// ---------------------------------------------------------------------------
__global__ __launch_bounds__(256) void gemm_bt(
    const unsigned short* __restrict__ A, const unsigned short* __restrict__ B,
    const float* __restrict__ bias, int Kp, int N,
    float* __restrict__ outF, int ldF, int nF,
    unsigned short* __restrict__ outB, int ldB, int nB, int relu)
{
    __shared__ __align__(16) unsigned short As[128 * 32];
    __shared__ __align__(16) unsigned short Bs[128 * 32];
    int tid = threadIdx.x;
    int w = tid >> 6, lane = tid & 63;
    int r = lane & 15, q = lane >> 4;
    int m0 = blockIdx.x * 128;
    int n0 = blockIdx.y * 128;
    int wm = (w >> 1) * 64, wn = (w & 1) * 64;
    f32x4 acc[4][4] = {};
    int ktiles = Kp >> 5;

    for (int kt = 0; kt < ktiles; ++kt) {
        int k0 = kt * 32;
#pragma unroll
        for (int iss = 0; iss < 2; ++iss) {
            int chunk = iss * 256 + w * 64 + lane;       // 0..511
            int mm = chunk >> 2, kc = chunk & 3;
            const unsigned short* ga = A + (size_t)(m0 + mm) * Kp + k0 + kc * 8;
            async16(ga, &As[(size_t)(iss * 256 + w * 64) * 8]);
            const unsigned short* gb = B + (size_t)(n0 + mm) * Kp + k0 + kc * 8;
            async16(gb, &Bs[(size_t)(iss * 256 + w * 64) * 8]);
        }
        __syncthreads();
        v8bf16 af[4], bfr[4];
#pragma unroll
        for (int im = 0; im < 4; ++im)
            af[im] = *(const v8bf16*)&As[(wm + im * 16 + r) * 32 + q * 8];
#pragma unroll
        for (int in = 0; in < 4; ++in)
            bfr[in] = *(const v8bf16*)&Bs[(wn + in * 16 + r) * 32 + q * 8];
#pragma unroll
        for (int im = 0; im < 4; ++im)
#pragma unroll
            for (int in = 0; in < 4; ++in)
                acc[im][in] = __builtin_amdgcn_mfma_f32_16x16x32_bf16(
                    af[im], bfr[in], acc[im][in], 0, 0, 0);
        __syncthreads();
    }

#pragma unroll
    for (int im = 0; im < 4; ++im) {
        int rowb = m0 + wm + im * 16 + q * 4;
#pragma unroll
        for (int in = 0; in < 4; ++in) {
            int col = n0 + wn + in * 16 + r;
            float bv = (col < N) ? bias[col] : 0.f;
#pragma unroll
            for (int reg = 0; reg < 4; ++reg) {
                float v = acc[im][in][reg];
                if (col < N) { v += bv; if (relu) v = fmaxf(v, 0.f); }
                else v = 0.f;
                int rr = rowb + reg;
                if (outF && col < nF) outF[(size_t)rr * ldF + col] = v;
                if (outB && col < nB) outB[(size_t)rr * ldB + col] = f2b(v);
            }
        }
    }
}

// ---------------------------------------------------------------------------
// 256x256 / BK=64 / 8-wave / 8-phase counted-vmcnt GEMM (T2+T3+T4+T5).
// Work remap: 7 consecutive work-ids share one A-tile (n varies fastest) and
// ids are chunked per-XCD (bijective, requires nwg%8==0) so the A-tile is
// L2-resident across its 7 uses; B (3.2 MB) stays L2-resident per XCD.
// ---------------------------------------------------------------------------
static __device__ __forceinline__ v8bf16 lds_frag256(
    const unsigned short* t /*256x64 tile*/, int row, int colB /*bytes*/)
{
    int o = row * 128 + (colB ^ (((row >> 2) & 1) << 5));
    return *(const v8bf16*)((const char*)t + o);
}

static __device__ __forceinline__ void stage_half(
    const unsigned short* __restrict__ G, int rowBase, int Kp, int kt,
    unsigned short* lh /*&lds[buf][op][half][0]*/, int w, int lane)
{
#pragma unroll
    for (int l = 0; l < 2; ++l) {
        int rowInHalf = l * 64 + w * 8 + (lane >> 3);
        // inverse-swizzled source column (bit5 of byte col XOR'd with dest bit9)
        int colE = (((lane & 7) * 16) ^ ((lane >> 5) << 5)) >> 1;
        const unsigned short* g =
            G + (size_t)(rowBase + rowInHalf) * Kp + kt * 64 + colE;
        async16(g, lh + l * 4096 + w * 512);   // HW adds lane*16 bytes
    }
}

__global__ __launch_bounds__(512, 2) void gemm_bt_8p(
    const unsigned short* __restrict__ A, const unsigned short* __restrict__ B,
    const float* __restrict__ bias, int Kp, int N,
    unsigned short* __restrict__ outB, int ldB)
{
    __shared__ __align__(16) unsigned short lds[2][2][2][128 * 64];
    const int tid = threadIdx.x;
    const int w = tid >> 6, lane = tid & 63;
    const int r = lane & 15, q = lane >> 4;

    // ---- work remap: XCD-chunked, n-fastest within an m-tile ----
    int d = blockIdx.y * gridDim.x + blockIdx.x;
    int nwg = gridDim.x * gridDim.y;
    int wrk = ((nwg & 7) == 0) ? ((d & 7) * (nwg >> 3) + (d >> 3)) : d;
    int ny = gridDim.y;
    int mt = wrk / ny, ntl = wrk - mt * ny;
    const int m0 = mt * 256;
    const int n0 = ntl * 256;

    const int wm = (w >> 2) * 128, wn = (w & 3) * 64;
    const int nt = Kp >> 6;        // K-tiles of 64
    const int niter = nt >> 1;     // 2 K-tiles per iteration

    f32x4 acc[8][4] = {};

    // prologue: stage A0,B0 (8 loads) + B1 (4 loads); wait A0,B0; B1 in flight
    stage_half(A, m0 + 0,   Kp, 0, &lds[0][0][0][0], w, lane);
    stage_half(A, m0 + 128, Kp, 0, &lds[0][0][1][0], w, lane);
    stage_half(B, n0 + 0,   Kp, 0, &lds[0][1][0][0], w, lane);
    stage_half(B, n0 + 128, Kp, 0, &lds[0][1][1][0], w, lane);
    stage_half(B, n0 + 0,   Kp, 1, &lds[1][1][0][0], w, lane);
    stage_half(B, n0 + 128, Kp, 1, &lds[1][1][1][0], w, lane);
    asm volatile("s_waitcnt vmcnt(4)");
    __builtin_amdgcn_sched_barrier(0);
    __builtin_amdgcn_s_barrier();

    for (int i = 0; i < niter; ++i) {
        const int T = 2 * i;
        const bool notLast = (i + 1 < niter);
#pragma unroll
        for (int tt = 0; tt < 2; ++tt) {               // tile T+tt in buf tt
            const unsigned short* At = &lds[tt][0][0][0];
            const unsigned short* Bt = &lds[tt][1][0][0];
            v8bf16 bf[4][2];
#pragma unroll
            for (int mp = 0; mp < 4; ++mp) {           // phase = tt*4 + mp + 1
                if (mp == 0) {
#pragma unroll
                    for (int in = 0; in < 4; ++in)
#pragma unroll
                        for (int kk = 0; kk < 2; ++kk)
                            bf[in][kk] = lds_frag256(Bt, wn + in * 16 + r,
                                                     kk * 64 + q * 16);
                }
                v8bf16 a0[2], a1[2];
#pragma unroll
                for (int kk = 0; kk < 2; ++kk) {
                    a0[kk] = lds_frag256(At, wm + (mp * 2 + 0) * 16 + r,
                                         kk * 64 + q * 16);
                    a1[kk] = lds_frag256(At, wm + (mp * 2 + 1) * 16 + r,
                                         kk * 64 + q * 16);
                }
                // staging schedule (each target region fully consumed >=1
                // barrier before its overwrite is issued):
                if (tt == 0 && mp == 0)
                    stage_half(A, m0 + 0,   Kp, T + 1, &lds[1][0][0][0], w, lane);
                if (tt == 0 && mp == 1) {
                    stage_half(A, m0 + 128, Kp, T + 1, &lds[1][0][1][0], w, lane);
                    if (notLast)
                        stage_half(B, n0 + 0,   Kp, T + 2, &lds[0][1][0][0], w, lane);
                }
                if (tt == 0 && mp == 2 && notLast)
                    stage_half(B, n0 + 128, Kp, T + 2, &lds[0][1][1][0], w, lane);
                if (tt == 1 && mp == 0 && notLast)
                    stage_half(A, m0 + 0,   Kp, T + 2, &lds[0][0][0][0], w, lane);
                if (tt == 1 && mp == 1 && notLast)
                    stage_half(A, m0 + 128, Kp, T + 2, &lds[0][0][1][0], w, lane);
                if (tt == 1 && mp == 2 && notLast)
                    stage_half(B, n0 + 0,   Kp, T + 3, &lds[1][1][0][0], w, lane);
                if (tt == 1 && mp == 3 && notLast)
                    stage_half(B, n0 + 128, Kp, T + 3, &lds[1][1][1][0], w, lane);

                if (mp == 3) {
                    if (notLast) {
                        asm volatile("s_waitcnt vmcnt(4)");   // keep next B in flight
                    } else if (tt == 0) {
                        asm volatile("s_waitcnt vmcnt(0)");   // drain for last tile
                    }
                    __builtin_amdgcn_sched_barrier(0);
                }
                __builtin_amdgcn_s_barrier();
                asm volatile("s_waitcnt lgkmcnt(0)");
                __builtin_amdgcn_sched_barrier(0);
                __builtin_amdgcn_s_setprio(1);
#pragma unroll
                for (int kk = 0; kk < 2; ++kk)
#pragma unroll
                    for (int in = 0; in < 4; ++in) {
                        acc[mp * 2 + 0][in] = __builtin_amdgcn_mfma_f32_16x16x32_bf16(
                            a0[kk], bf[in][kk], acc[mp * 2 + 0][in], 0, 0, 0);
                        acc[mp * 2 + 1][in] = __builtin_amdgcn_mfma_f32_16x16x32_bf16(
                            a1[kk], bf[in][kk], acc[mp * 2 + 1][in], 0, 0, 0);
                    }
                __builtin_amdgcn_s_setprio(0);
                __builtin_amdgcn_s_barrier();
            }
        }
    }

#pragma unroll
    for (int im = 0; im < 8; ++im) {
        int rowb = m0 + wm + im * 16 + q * 4;
#pragma unroll
        for (int in = 0; in < 4; ++in) {
            int col = n0 + wn + in * 16 + r;
            float bv = (col < N) ? bias[col] : 0.f;
#pragma unroll
            for (int reg = 0; reg < 4; ++reg) {
                float v = (col < N) ? acc[im][in][reg] + bv : 0.f;
                outB[(size_t)(rowb + reg) * ldB + col] = f2b(v);
            }
        }
    }
}

// ---------------------------------------------------------------------------
// Attention per b: S=QK^T via MFMA, softmax w/ mask, pbar_h = mean_i P_h.
// Output: fbar[b] = [ sum_j pbar0[j]*full[j] (KP) | sum_j pbar1[j]*full[j] (KP) ]
// (V- and out-projections are folded into the downstream Wfold GEMM.)
// ---------------------------------------------------------------------------
static __device__ __forceinline__ v8bf16 load_frag(
    const unsigned short* row, int colbase, int d0)
{
    union { unsigned u[4]; v8bf16 v; unsigned short s[8]; } U;
    if (d0 + 8 <= DHH) {
        const unsigned* p = (const unsigned*)(row + colbase + d0);
        U.u[0] = p[0]; U.u[1] = p[1]; U.u[2] = p[2]; U.u[3] = p[3];
    } else {
#pragma unroll
        for (int t = 0; t < 8; ++t)
            U.s[t] = (d0 + t < DHH) ? row[colbase + d0 + t] : (unsigned short)0;
    }
    return U.v;
}

__global__ __launch_bounds__(256) void attn_kernel(
    const unsigned short* __restrict__ qkv,   // chunk rows x LDQ (q|k)
    const unsigned short* __restrict__ fullr, // chunk rows x KP
    const int* __restrict__ hist_nids,
    unsigned short* __restrict__ fbar,        // BSZ x 2*KP bf16
    int c0)
{
    __shared__ float Sp[2][2][LH][LH];
    __shared__ float P[2][LH][LH];
    __shared__ float pbar[2][LH];
    __shared__ int maskv[LH];
    int b = c0 + blockIdx.x;
    int tid = threadIdx.x;
    int lane = tid & 63, w = tid >> 6;
    int r = lane & 15, q = lane >> 4;
    if (tid < LH) maskv[tid] = (hist_nids[b * LH + tid] == 0 && tid != LH - 1) ? 1 : 0;

    const unsigned short* base = qkv + (size_t)blockIdx.x * LH * LDQ;
    int h = w & 1, kh = w >> 1;
    int qoff = h * DHH;
    int koff = KOFF + h * DHH;
    f32x4 sacc[2][2] = {};
#pragma unroll
    for (int step = 0; step < 7; ++step) {
        int k0 = kh * 224 + step * 32;
        v8bf16 qf[2], kf[2];
#pragma unroll
        for (int im = 0; im < 2; ++im) {
            int mm = im * 16 + r; if (mm >= LH) mm = LH - 1;
            const unsigned short* rp = base + (size_t)mm * LDQ;
            qf[im] = load_frag(rp, qoff, k0 + q * 8);
            kf[im] = load_frag(rp, koff, k0 + q * 8);
        }
#pragma unroll
        for (int im = 0; im < 2; ++im)
#pragma unroll
            for (int in = 0; in < 2; ++in)
                sacc[im][in] = __builtin_amdgcn_mfma_f32_16x16x32_bf16(
                    qf[im], kf[in], sacc[im][in], 0, 0, 0);
    }
#pragma unroll
    for (int im = 0; im < 2; ++im)
#pragma unroll
        for (int in = 0; in < 2; ++in)
#pragma unroll
            for (int reg = 0; reg < 4; ++reg) {
                int i = im * 16 + q * 4 + reg, jj = in * 16 + r;
                if (i < LH && jj < LH) Sp[h][kh][i][jj] = sacc[im][in][reg];
            }
    __syncthreads();

    if (tid < 2 * LH) {
        int hh = tid / LH, i = tid - (tid / LH) * LH;
        const float scale = 0.0482242822f;  // 1/sqrt(430)
        float s[LH], mx = -1e30f;
#pragma unroll
        for (int jj = 0; jj < LH; ++jj) {
            float v = (Sp[hh][0][i][jj] + Sp[hh][1][i][jj]) * scale;
            if (maskv[jj]) v = -1e30f;
            s[jj] = v; mx = fmaxf(mx, v);
        }
        float sum = 0.f;
#pragma unroll
        for (int jj = 0; jj < LH; ++jj) { float e = expf(s[jj] - mx); s[jj] = e; sum += e; }
        float inv = 1.f / sum;
#pragma unroll
        for (int jj = 0; jj < LH; ++jj) P[hh][i][jj] = s[jj] * inv;
    }
    __syncthreads();
    if (tid < 2 * LH) {
        int hh = tid / LH, jj = tid - (tid / LH) * LH;
        float a = 0.f;
#pragma unroll
        for (int i = 0; i < LH; ++i) a += P[hh][i][jj];
        pbar[hh][jj] = a * (1.f / LH);
    }
    __syncthreads();

    const unsigned short* fb = fullr + (size_t)blockIdx.x * LH * KP;
    for (int k = tid; k < KP; k += 256) {
        float a0 = 0.f, a1 = 0.f;
#pragma unroll
        for (int jj = 0; jj < LH; ++jj) {
            float v = b2f(fb[(size_t)jj * KP + k]);
            a0 += pbar[0][jj] * v;
            a1 += pbar[1][jj] * v;
        }
        fbar[(size_t)b * (2 * KP) + k]      = f2b(a0);
        fbar[(size_t)b * (2 * KP) + KP + k] = f2b(a1);
    }
}

// ---------------------------------------------------------------------------
extern "C" void kernel_launch(void* const* d_in, const int* in_sizes, int n_in,
                              void* d_out, int out_size, void* d_ws, size_t ws_size,
                              hipStream_t stream)
{
    const int*   nids      = (const int*)d_in[0];
    const int*   hist_nids = (const int*)d_in[1];
    const int*   aids      = (const int*)d_in[2];
    const int*   eids      = (const int*)d_in[3];
    const float* hist_ts   = (const float*)d_in[4];
    const int*   dirs      = (const int*)d_in[5];
    const float* node_emb  = (const float*)d_in[6];
    const float* edge_emb  = (const float*)d_in[7];
    const float* anony_emb = (const float*)d_in[8];
    const float* time_w    = (const float*)d_in[9];
    const float* time_b    = (const float*)d_in[10];
    const float* in_proj_w = (const float*)d_in[11];
    const float* in_proj_b = (const float*)d_in[12];
    const float* out_proj_w= (const float*)d_in[13];
    const float* out_proj_b= (const float*)d_in[14];
    const float* outfn_w   = (const float*)d_in[15];
    const float* outfn_b   = (const float*)d_in[16];
    const float* fc1_w     = (const float*)d_in[17];
    const float* fc1_b     = (const float*)d_in[18];
    const float* fc2_w     = (const float*)d_in[19];
    const float* fc2_b     = (const float*)d_in[20];

    float* out_left  = (float*)d_out;
    float* out_right = out_left + (size_t)BSZ * NFD;
    float* out_ts    = out_right + (size_t)BSZ * NFD;

    char* p = (char*)d_ws;
    auto alloc = [&](size_t bytes) -> char* {
        char* r = p; p += (bytes + 255) & ~(size_t)255; return r;
    };
    unsigned short* Wqk  = (unsigned short*)alloc((size_t)NQK * KP * 2);
    unsigned short* Bv   = (unsigned short*)alloc((size_t)NQK * KP * 2);
    unsigned short* Wfold= (unsigned short*)alloc((size_t)896 * NQK * 2);
    unsigned short* Wop  = (unsigned short*)alloc((size_t)896 * KP * 2);
    unsigned short* Wofn = (unsigned short*)alloc((size_t)256 * KP * 2);
    unsigned short* Wfc1 = (unsigned short*)alloc((size_t)256 * KP * 2);
    unsigned short* Wfc2 = (unsigned short*)alloc((size_t)256 * 192 * 2);
    float* qkbias = (float*)alloc((size_t)NQK * 4);
    float* bprime = (float*)alloc((size_t)896 * 4);
    float* zbias  = (float*)alloc((size_t)NQK * 4);
    unsigned short* fbarb = (unsigned short*)alloc((size_t)BSZ * 2 * KP * 2);
    unsigned short* xbuf  = (unsigned short*)alloc((size_t)BSZ * KP * 2);
    unsigned short* tmp1  = (unsigned short*)alloc((size_t)BSZ * 896 * 2);
    unsigned short* hbuf  = (unsigned short*)alloc((size_t)BSZ * 192 * 2);
    size_t fixed = (size_t)(p - (char*)d_ws);

    int CB = 2048;  // chunk of batch; full+qkv chunk ~220MB stays L3-resident
    while (CB > 128) {
        size_t need = fixed + (size_t)CB * LH * KP * 2 + (size_t)CB * LH * LDQ * 2 + 4096;
        if (need <= ws_size) break;
        CB >>= 1;
    }
    unsigned short* fullc = (unsigned short*)alloc((size_t)CB * LH * KP * 2);
    unsigned short* qkvc  = (unsigned short*)alloc((size_t)CB * LH * LDQ * 2);

    prep_all<<<dim3(PREP_BLOCKS), dim3(256), 0, stream>>>(
        in_proj_w, out_proj_w, outfn_w, fc1_w, fc2_w, in_proj_b, out_proj_b,
        Wqk, Bv, Wop, Wofn, Wfc1, Wfc2, qkbias, zbias, bprime);
    // Wfold[896 x NQK] = Wop @ Wvcat   (A=Wop bf16, B=Bv, K=896)
    gemm_bt<<<dim3(896 / 128, NQK / 128), dim3(256), 0, stream>>>(
        Wop, Bv, zbias, KP, NQK,
        (float*)nullptr, 0, 0, Wfold, NQK, NQK, 0);

    for (int c0 = 0; c0 < BSZ; c0 += CB) {
        build_kernel<<<dim3(CB * LH), dim3(256), 0, stream>>>(
            nids, hist_nids, aids, eids, hist_ts, dirs,
            node_emb, edge_emb, anony_emb, time_w, time_b,
            fullc, xbuf, out_ts, c0);
        gemm_bt_8p<<<dim3(CB * LH / 256, NQK / 256), dim3(512), 0, stream>>>(
            fullc, Wqk, qkbias, KP, NQK, qkvc, LDQ);
        attn_kernel<<<dim3(CB), dim3(256), 0, stream>>>(
            qkvc, fullc, hist_nids, fbarb, c0);
    }
    // E1 (folded): tmp1 = relu(fbar @ Wfold^T + bprime), K=1792
    gemm_bt<<<dim3(BSZ / 128, 7), dim3(256), 0, stream>>>(
        fbarb, Wfold, bprime, NQK, DD,
        (float*)nullptr, 0, 0, tmp1, 896, 896, 1);
    // E2: h_prev_left = tmp1 @ Wofn^T + b  -> d_out (fp32) and x cols 0..171 (bf16)
    gemm_bt<<<dim3(BSZ / 128, 2), dim3(256), 0, stream>>>(
        tmp1, Wofn, outfn_b, 896, NFD,
        out_left, NFD, NFD, xbuf, KP, NFD, 0);
    // E3: h = relu(x @ Wfc1^T + b) -> bf16 (zero-padded to 192)
    gemm_bt<<<dim3(BSZ / 128, 2), dim3(256), 0, stream>>>(
        xbuf, Wfc1, fc1_b, KP, NFD,
        (float*)nullptr, 0, 0, hbuf, 192, 192, 1);
    // E4: h_prev_right = h @ Wfc2^T + b -> d_out
    gemm_bt<<<dim3(BSZ / 128, 2), dim3(256), 0, stream>>>(
        hbuf, Wfc2, fc2_b, 192, NFD,
        out_right, NFD, NFD, (unsigned short*)nullptr, 0, 0, 0);
}